// Round 2
// baseline (341.948 us; speedup 1.0000x reference)
//
#include <hip/hip_runtime.h>

using bf16x8 = __attribute__((ext_vector_type(8))) short;
using f32x4  = __attribute__((ext_vector_type(4))) float;

__device__ __forceinline__ unsigned short f2bf(float f) {
  unsigned u = __builtin_bit_cast(unsigned, f);
  u += 0x7fffu + ((u >> 16) & 1u);
  return (unsigned short)(u >> 16);
}

// Convert + transpose weights to bf16 each launch (d_ws is re-poisoned every call).
// ws layout: [0 .. 49151]  wT_qkv  [384][128]  (wT[c][k] = w_qkv[k][c])
//            [49152 .. ]   wT_proj [128][128]  (wT[c][k] = w_proj[k][c])
__global__ void prep_weights(const float* __restrict__ wqkv,
                             const float* __restrict__ wproj,
                             unsigned short* __restrict__ ws) {
  int idx = blockIdx.x * 256 + threadIdx.x;   // 65536 threads
  if (idx < 49152) {
    int c = idx >> 7, k = idx & 127;
    ws[idx] = f2bf(wqkv[k * 384 + c]);
  } else {
    int i = idx - 49152;
    int c = i >> 7, k = i & 127;
    ws[49152 + i] = f2bf(wproj[k * 128 + c]);
  }
}

// One block (4 waves) per window. N=64 rows, C=128 channels.
// MFMA 16x16x32 bf16 layouts:
//   A: row = lane&15, k = 8*(lane>>4)+e  (contiguous 16B per lane)
//   B: col = lane&15, k = 8*(lane>>4)+e
//   D: col = lane&15, row = 4*(lane>>4)+reg
__global__ __launch_bounds__(256) void win_attn(
    const float* __restrict__ x, const float* __restrict__ bqkv,
    const float* __restrict__ bproj, const unsigned short* __restrict__ ws,
    float* __restrict__ out) {
  // Overlaid LDS buffers (strides 136/72 shorts = 68/36 dwords -> 2-way bank alias only)
  __shared__ unsigned short sA[9216];   // x [64][136]  ->  vT [128][72]
  __shared__ unsigned short sB[8704];   // q [64][136]  ->  O  [64][136]
  __shared__ unsigned short sC[8704];   // k [64][136]  ->  P  [64][72]

  const int tid  = threadIdx.x;
  const int wave = tid >> 6;
  const int lane = tid & 63;
  const int g    = lane >> 4;     // 16-lane group 0..3
  const int lr   = lane & 15;
  const int b    = blockIdx.x;
  const float* xb = x + (size_t)b * 8192;

  // ---- stage 0: load x window (64x128 f32) -> sA bf16 ----
  #pragma unroll
  for (int i = 0; i < 8; ++i) {
    int e = tid + 256 * i;                  // float4 index
    float4 v = ((const float4*)xb)[e];
    int flat = e << 2;
    int r = flat >> 7, c = flat & 127;
    ushort4 pk = make_ushort4(f2bf(v.x), f2bf(v.y), f2bf(v.z), f2bf(v.w));
    *(ushort4*)&sA[r * 136 + c] = pk;
  }
  __syncthreads();

  // ---- stage 1: qkv = x @ w_qkv ; wave w owns output cols [96w, 96w+96) ----
  f32x4 acc[4][6];
  #pragma unroll
  for (int rt = 0; rt < 4; ++rt)
    #pragma unroll
    for (int ct = 0; ct < 6; ++ct)
      acc[rt][ct] = f32x4{0.f, 0.f, 0.f, 0.f};

  float bias[6];
  #pragma unroll
  for (int ct = 0; ct < 6; ++ct) bias[ct] = bqkv[96 * wave + 16 * ct + lr];

  #pragma unroll
  for (int k0 = 0; k0 < 128; k0 += 32) {
    bf16x8 a[4];
    #pragma unroll
    for (int rt = 0; rt < 4; ++rt)
      a[rt] = *(const bf16x8*)&sA[(16 * rt + lr) * 136 + k0 + 8 * g];
    #pragma unroll
    for (int ct = 0; ct < 6; ++ct) {
      bf16x8 bf = *(const bf16x8*)&ws[(96 * wave + 16 * ct + lr) * 128 + k0 + 8 * g];
      #pragma unroll
      for (int rt = 0; rt < 4; ++rt)
        acc[rt][ct] = __builtin_amdgcn_mfma_f32_16x16x32_bf16(a[rt], bf, acc[rt][ct], 0, 0, 0);
    }
  }
  __syncthreads();   // all x reads done before vT overlays sA

  // ---- stage 1 epilogue: +bias, route q->sB, k->sC, v^T->sA ----
  #pragma unroll
  for (int rt = 0; rt < 4; ++rt) {
    #pragma unroll
    for (int ct = 0; ct < 6; ++ct) {
      int c  = 96 * wave + 16 * ct + lr;     // wave-uniform branch below
      int r0 = 16 * rt + 4 * g;
      f32x4 v = acc[rt][ct];
      float bb = bias[ct];
      if (c < 128) {
        #pragma unroll
        for (int j = 0; j < 4; ++j) sB[(r0 + j) * 136 + c] = f2bf(v[j] + bb);
      } else if (c < 256) {
        #pragma unroll
        for (int j = 0; j < 4; ++j) sC[(r0 + j) * 136 + (c - 128)] = f2bf(v[j] + bb);
      } else {
        ushort4 pk = make_ushort4(f2bf(v[0] + bb), f2bf(v[1] + bb),
                                  f2bf(v[2] + bb), f2bf(v[3] + bb));
        *(ushort4*)&sA[(c - 256) * 72 + r0] = pk;   // vT[c][r0..r0+3]
      }
    }
  }
  __syncthreads();

  // ---- stage 2: S = q @ k^T ; wave w owns rows [16w, 16w+16) ----
  f32x4 s[4];
  #pragma unroll
  for (int ct = 0; ct < 4; ++ct) s[ct] = f32x4{0.f, 0.f, 0.f, 0.f};
  #pragma unroll
  for (int k0 = 0; k0 < 128; k0 += 32) {
    bf16x8 a = *(const bf16x8*)&sB[(16 * wave + lr) * 136 + k0 + 8 * g];
    #pragma unroll
    for (int ct = 0; ct < 4; ++ct) {
      bf16x8 bf = *(const bf16x8*)&sC[(16 * ct + lr) * 136 + k0 + 8 * g];
      s[ct] = __builtin_amdgcn_mfma_f32_16x16x32_bf16(a, bf, s[ct], 0, 0, 0);
    }
  }
  __syncthreads();   // everyone done reading k before P overlays sC

  // ---- stage 3: softmax over 64 cols per row (rows 4g+j of this wave) ----
  const float scale = 0.08838834764831845f;      // 1/sqrt(128)
  const float l2e   = 1.4426950408889634f;
  float rs[4];
  #pragma unroll
  for (int j = 0; j < 4; ++j) {
    float mm = fmaxf(fmaxf(s[0][j], s[1][j]), fmaxf(s[2][j], s[3][j])) * scale;
    #pragma unroll
    for (int off = 1; off < 16; off <<= 1) mm = fmaxf(mm, __shfl_xor(mm, off, 64));
    float ss = 0.f;
    #pragma unroll
    for (int ct = 0; ct < 4; ++ct) {
      float p = exp2f((s[ct][j] * scale - mm) * l2e);
      s[ct][j] = p;
      ss += p;
    }
    #pragma unroll
    for (int off = 1; off < 16; off <<= 1) ss += __shfl_xor(ss, off, 64);
    rs[j] = 1.0f / ss;                            // fold 1/sum into PV epilogue
  }
  // write unnormalized P (<=1) to sC overlay [64][72]
  #pragma unroll
  for (int ct = 0; ct < 4; ++ct)
    #pragma unroll
    for (int j = 0; j < 4; ++j)
      sC[(16 * wave + 4 * g + j) * 72 + 16 * ct + lr] = f2bf(s[ct][j]);
  __syncthreads();

  // ---- stage 4: O = P @ v ; wave w owns rows [16w, 16w+16) ----
  f32x4 o[8];
  #pragma unroll
  for (int ct = 0; ct < 8; ++ct) o[ct] = f32x4{0.f, 0.f, 0.f, 0.f};
  #pragma unroll
  for (int k0 = 0; k0 < 64; k0 += 32) {
    bf16x8 a = *(const bf16x8*)&sC[(16 * wave + lr) * 72 + k0 + 8 * g];
    #pragma unroll
    for (int ct = 0; ct < 8; ++ct) {
      bf16x8 bf = *(const bf16x8*)&sA[(16 * ct + lr) * 72 + k0 + 8 * g];  // vT rows = channels
      o[ct] = __builtin_amdgcn_mfma_f32_16x16x32_bf16(a, bf, o[ct], 0, 0, 0);
    }
  }
  // normalize rows and write O -> sB overlay [64][136] (q is dead since stage-2 barrier)
  #pragma unroll
  for (int ct = 0; ct < 8; ++ct)
    #pragma unroll
    for (int j = 0; j < 4; ++j)
      sB[(16 * wave + 4 * g + j) * 136 + 16 * ct + lr] = f2bf(o[ct][j] * rs[j]);
  __syncthreads();

  // ---- stage 5: y = O @ w_proj + b_proj ; wave w owns rows [16w,16w+16) ----
  f32x4 y[8];
  #pragma unroll
  for (int ct = 0; ct < 8; ++ct) y[ct] = f32x4{0.f, 0.f, 0.f, 0.f};
  const unsigned short* wp = ws + 49152;
  #pragma unroll
  for (int k0 = 0; k0 < 128; k0 += 32) {
    bf16x8 a = *(const bf16x8*)&sB[(16 * wave + lr) * 136 + k0 + 8 * g];
    #pragma unroll
    for (int ct = 0; ct < 8; ++ct) {
      bf16x8 bf = *(const bf16x8*)&wp[(16 * ct + lr) * 128 + k0 + 8 * g];
      y[ct] = __builtin_amdgcn_mfma_f32_16x16x32_bf16(a, bf, y[ct], 0, 0, 0);
    }
  }
  float* ob = out + (size_t)b * 8192;
  #pragma unroll
  for (int ct = 0; ct < 8; ++ct) {
    float bb = bproj[16 * ct + lr];
    #pragma unroll
    for (int j = 0; j < 4; ++j) {
      int r = 16 * wave + 4 * g + j, c = 16 * ct + lr;
      ob[r * 128 + c] = y[ct][j] + bb;
    }
  }
}

extern "C" void kernel_launch(void* const* d_in, const int* in_sizes, int n_in,
                              void* d_out, int out_size, void* d_ws, size_t ws_size,
                              hipStream_t stream) {
  const float* x     = (const float*)d_in[0];
  const float* wqkv  = (const float*)d_in[1];
  const float* bqkv  = (const float*)d_in[2];
  const float* wproj = (const float*)d_in[3];
  const float* bproj = (const float*)d_in[4];
  float* out = (float*)d_out;
  unsigned short* ws = (unsigned short*)d_ws;   // needs 128 KiB

  prep_weights<<<256, 256, 0, stream>>>(wqkv, wproj, ws);
  win_attn<<<4096, 256, 0, stream>>>(x, bqkv, bproj, ws, out);
}